// Round 9
// baseline (134.966 us; speedup 1.0000x reference)
//
#include <hip/hip_runtime.h>
#include <hip/hip_bf16.h>
#include <math.h>

#define S_LEN  2048
#define DMODEL 512
#define NHEADS 8
#define DK     64
#define WIN    64

static constexpr float SCALE = 0.125f;

typedef short bf16x8 __attribute__((ext_vector_type(8)));
typedef float f32x4  __attribute__((ext_vector_type(4)));

// ---------------------------------------------------------------------------
// helpers
// ---------------------------------------------------------------------------
__device__ __forceinline__ short bfh(float v)
{
    __hip_bfloat16 b = __float2bfloat16(v);
    return *reinterpret_cast<short*>(&b);
}
__device__ __forceinline__ float bf2f(short s)
{
    __hip_bfloat16 b = *reinterpret_cast<__hip_bfloat16*>(&s);
    return __bfloat162float(b);
}
__device__ __forceinline__ void split1(float v, short& h, short& l)
{
    h = bfh(v);
    l = bfh(v - bf2f(h));
}
// 8 fp32 -> bf16 hi/lo fragments
__device__ __forceinline__ void splitx8(const float4 a0, const float4 a1,
                                        bf16x8& h8, bf16x8& l8)
{
    float f[8] = {a0.x, a0.y, a0.z, a0.w, a1.x, a1.y, a1.z, a1.w};
#pragma unroll
    for (int i = 0; i < 8; ++i) {
        short hh, ll;
        split1(f[i], hh, ll);
        h8[i] = hh;
        l8[i] = ll;
    }
}

// ---------------------------------------------------------------------------
// weight cast: z=0..3 -> Wq,Wk,Wv,Wo fp32 -> bf16
// ---------------------------------------------------------------------------
__global__ __launch_bounds__(256)
void cast_w(const float* __restrict__ wq, const float* __restrict__ wk,
            const float* __restrict__ wv, const float* __restrict__ wo,
            short* __restrict__ wqb, short* __restrict__ wkb,
            short* __restrict__ wvb, short* __restrict__ wob)
{
    const float* s; short* d;
    switch (blockIdx.z) {
        case 0:  s = wq; d = wqb; break;
        case 1:  s = wk; d = wkb; break;
        case 2:  s = wv; d = wvb; break;
        default: s = wo; d = wob; break;
    }
    for (int i = blockIdx.x * 256 + threadIdx.x; i < 65536; i += gridDim.x * 256) {
        const float4 v = ((const float4*)s)[i];
        short4 o;
        o.x = bfh(v.x); o.y = bfh(v.y); o.z = bfh(v.z); o.w = bfh(v.w);
        ((short4*)d)[i] = o;
    }
}

// ---------------------------------------------------------------------------
// QKV GEMM, zero-LDS streaming: all operands straight from global (L2-hot).
// 256 threads = 4 waves; tile 64 rows x 64 cols; wave = 16 rows x 64 cols.
// A: fp32 x, split hi/lo in-register. B: bf16 weights (pre-cast).
// No __syncthreads anywhere; fully unrolled K-loop pipelines on vmcnt.
// z=0 -> Q (bf16 hi/lo), z=1 -> K (bf16), z=2 -> V^T (bf16, [dim][pos]).
// ---------------------------------------------------------------------------
__global__ __launch_bounds__(256)
void gemm_qkv6(const float* __restrict__ x,
               const short* __restrict__ wqb, const short* __restrict__ wkb,
               const short* __restrict__ wvb,
               const float* __restrict__ bq, const float* __restrict__ bk,
               const float* __restrict__ bv,
               short* __restrict__ qh, short* __restrict__ ql,
               short* __restrict__ kb, short* __restrict__ vbt)
{
    const int z = blockIdx.z;
    const short* Bg   = (z == 0) ? wqb : (z == 1) ? wkb : wvb;
    const float* bias = (z == 0) ? bq  : (z == 1) ? bk  : bv;
    const int row0 = blockIdx.y * 64;
    const int col0 = blockIdx.x * 64;
    const int tid  = threadIdx.x;
    const int lane = tid & 63;
    const int wv   = tid >> 6;
    const int col  = lane & 15;
    const int quad = lane >> 4;
    const int m    = row0 + wv * 16 + col;       // this wave's A row

    f32x4 acc[4];
#pragma unroll
    for (int nj = 0; nj < 4; ++nj)
        acc[nj] = (f32x4)0.0f;

#pragma unroll 4
    for (int kc = 0; kc < 16; ++kc) {
        const float* xp = x + (size_t)m * 512 + kc * 32 + quad * 8;
        const float4 a0 = *(const float4*)xp;
        const float4 a1 = *(const float4*)(xp + 4);
        bf16x8 ah, al;
        splitx8(a0, a1, ah, al);
#pragma unroll
        for (int nj = 0; nj < 4; ++nj) {
            const int n = col0 + nj * 16 + col;
            const bf16x8 bf = *(const bf16x8*)(Bg + (size_t)n * 512 + kc * 32 + quad * 8);
            acc[nj] = __builtin_amdgcn_mfma_f32_16x16x32_bf16(ah, bf, acc[nj], 0, 0, 0);
            acc[nj] = __builtin_amdgcn_mfma_f32_16x16x32_bf16(al, bf, acc[nj], 0, 0, 0);
        }
    }

    // epilogue
#pragma unroll
    for (int nj = 0; nj < 4; ++nj) {
        const int cc = col0 + nj * 16 + col;
        const float bias_v = bias[cc];
#pragma unroll
        for (int e = 0; e < 4; ++e) {
            const int row = row0 + wv * 16 + quad * 4 + e;
            const float val = acc[nj][e] + bias_v;
            if (z == 0) {
                short hh, ll;
                split1(val, hh, ll);
                qh[(size_t)row * 512 + cc] = hh;
                ql[(size_t)row * 512 + cc] = ll;
            } else if (z == 1) {
                kb[(size_t)row * 512 + cc] = bfh(val);
            } else {
                vbt[(size_t)cc * 2048 + row] = bfh(val);   // transposed
            }
        }
    }
}

// ---------------------------------------------------------------------------
// Output projection, zero-LDS streaming. 128 threads = 2 waves;
// tile 32 rows x 64 cols; wave = 16 rows. A = attn output bf16, B = Wo bf16.
// ---------------------------------------------------------------------------
__global__ __launch_bounds__(128)
void gemm_out6(const short* __restrict__ ah_g,
               const short* __restrict__ wob, const float* __restrict__ bo,
               float* __restrict__ out)
{
    const int row0 = blockIdx.y * 32;
    const int col0 = blockIdx.x * 64;
    const int tid  = threadIdx.x;
    const int lane = tid & 63;
    const int wv   = tid >> 6;
    const int col  = lane & 15;
    const int quad = lane >> 4;
    const int m    = row0 + wv * 16 + col;

    f32x4 acc[4];
#pragma unroll
    for (int nj = 0; nj < 4; ++nj)
        acc[nj] = (f32x4)0.0f;

#pragma unroll
    for (int kc = 0; kc < 16; ++kc) {
        const bf16x8 af = *(const bf16x8*)(ah_g + (size_t)m * 512 + kc * 32 + quad * 8);
#pragma unroll
        for (int nj = 0; nj < 4; ++nj) {
            const int n = col0 + nj * 16 + col;
            const bf16x8 bf = *(const bf16x8*)(wob + (size_t)n * 512 + kc * 32 + quad * 8);
            acc[nj] = __builtin_amdgcn_mfma_f32_16x16x32_bf16(af, bf, acc[nj], 0, 0, 0);
        }
    }

#pragma unroll
    for (int nj = 0; nj < 4; ++nj) {
        const int cc = col0 + nj * 16 + col;
        const float bias_v = bo[cc];
#pragma unroll
        for (int e = 0; e < 4; ++e) {
            const int row = row0 + wv * 16 + quad * 4 + e;
            out[(size_t)row * 512 + cc] = acc[nj][e] + bias_v;
        }
    }
}

// ---------------------------------------------------------------------------
// MFMA banded attention, near-zero LDS: Q/K/V fragments straight from global
// (L2-hot). Only the P C-layout -> A-layout transform goes through LDS.
// Window-chunk alignment: chunk starts are =0 mod 8, boundaries 0/2048 are
// =0 mod 8 -> no chunk straddles validity; clamped loads are P=0-masked.
// Block = (head, 32-query tile), 256 thr = 4 waves.
// ---------------------------------------------------------------------------
__global__ __launch_bounds__(256)
void banded_attn5(const short* __restrict__ qh, const short* __restrict__ ql,
                  const short* __restrict__ kb, const short* __restrict__ vbt,
                  short* __restrict__ abh)
{
    __shared__ __align__(16) short PS[32 * 200];    // P [32 rows][192+pad]
    __shared__ float pmax[4][32];
    __shared__ float psum[4][32];

    const int h    = blockIdx.x;
    const int t0   = blockIdx.y * 32;
    const int tid  = threadIdx.x;
    const int lane = tid & 63;
    const int wv   = tid >> 6;
    const int col  = lane & 15;
    const int quad = lane >> 4;

    // ---- QK^T: wave covers window positions [wv*48, wv*48+48) ----
    f32x4 sacc[2][3];
#pragma unroll
    for (int mi = 0; mi < 2; ++mi)
#pragma unroll
        for (int nj = 0; nj < 3; ++nj)
            sacc[mi][nj] = (f32x4)0.0f;

#pragma unroll
    for (int ks = 0; ks < 2; ++ks) {
        bf16x8 aqh[2], aql[2];
#pragma unroll
        for (int mi = 0; mi < 2; ++mi) {
            const size_t qoff = (size_t)(t0 + mi * 16 + col) * 512 + h * 64 + ks * 32 + quad * 8;
            aqh[mi] = *(const bf16x8*)(qh + qoff);
            aql[mi] = *(const bf16x8*)(ql + qoff);
        }
#pragma unroll
        for (int nj = 0; nj < 3; ++nj) {
            const int n = wv * 48 + nj * 16 + col;
            int pos = t0 - 64 + n;
            pos = pos < 0 ? 0 : (pos > 2047 ? 2047 : pos);   // masked below
            const bf16x8 bkf = *(const bf16x8*)(kb + (size_t)pos * 512 + h * 64 + ks * 32 + quad * 8);
#pragma unroll
            for (int mi = 0; mi < 2; ++mi) {
                sacc[mi][nj] = __builtin_amdgcn_mfma_f32_16x16x32_bf16(aqh[mi], bkf, sacc[mi][nj], 0, 0, 0);
                sacc[mi][nj] = __builtin_amdgcn_mfma_f32_16x16x32_bf16(aql[mi], bkf, sacc[mi][nj], 0, 0, 0);
            }
        }
    }

    // ---- mask + scale ----
    float pv[2][3][4];
#pragma unroll
    for (int mi = 0; mi < 2; ++mi)
#pragma unroll
        for (int nj = 0; nj < 3; ++nj)
#pragma unroll
            for (int e = 0; e < 4; ++e) {
                const int r32 = mi * 16 + quad * 4 + e;
                const int n   = wv * 48 + nj * 16 + col;
                const int pos = t0 - 64 + n;
                const int d   = n - r32;
                const bool valid = (pos >= 0) && (pos < S_LEN) && (d >= 0) && (d <= 128);
                pv[mi][nj][e] = valid ? sacc[mi][nj][e] * SCALE : -__builtin_inff();
            }

    // ---- wave-partial row max ----
#pragma unroll
    for (int mi = 0; mi < 2; ++mi)
#pragma unroll
        for (int e = 0; e < 4; ++e) {
            float mx = fmaxf(fmaxf(pv[mi][0][e], pv[mi][1][e]), pv[mi][2][e]);
#pragma unroll
            for (int off = 1; off < 16; off <<= 1)
                mx = fmaxf(mx, __shfl_xor(mx, off));
            if ((lane & 15) == 0) pmax[wv][mi * 16 + quad * 4 + e] = mx;
        }
    __syncthreads();

    // ---- exp + wave-partial sums + write P (bf16) to LDS ----
#pragma unroll
    for (int mi = 0; mi < 2; ++mi)
#pragma unroll
        for (int e = 0; e < 4; ++e) {
            const int r32 = mi * 16 + quad * 4 + e;
            const float m = fmaxf(fmaxf(pmax[0][r32], pmax[1][r32]),
                                  fmaxf(pmax[2][r32], pmax[3][r32]));
            float ss = 0.f;
#pragma unroll
            for (int nj = 0; nj < 3; ++nj) {
                const float p = __expf(pv[mi][nj][e] - m);
                pv[mi][nj][e] = p;
                ss += p;
            }
#pragma unroll
            for (int off = 1; off < 16; off <<= 1)
                ss += __shfl_xor(ss, off);
            if ((lane & 15) == 0) psum[wv][r32] = ss;
#pragma unroll
            for (int nj = 0; nj < 3; ++nj) {
                const int n = wv * 48 + nj * 16 + col;
                PS[r32 * 200 + n] = bfh(pv[mi][nj][e]);
            }
        }
    __syncthreads();

    // ---- PV: P from LDS (A-layout), V^T straight from global ----
    const int mi = wv >> 1;
    f32x4 oacc[2];
    oacc[0] = (f32x4)0.0f;
    oacc[1] = (f32x4)0.0f;
#pragma unroll
    for (int ks = 0; ks < 6; ++ks) {
        const bf16x8 pa = *(const bf16x8*)&PS[(mi * 16 + col) * 200 + ks * 32 + quad * 8];
        int wpos = t0 - 64 + ks * 32 + quad * 8;
        wpos = wpos < 0 ? 0 : (wpos > 2040 ? 2040 : wpos);   // whole-chunk masked
#pragma unroll
        for (int t = 0; t < 2; ++t) {
            const int d = ((wv & 1) * 2 + t) * 16 + col;
            const bf16x8 vf = *(const bf16x8*)(vbt + (size_t)(h * 64 + d) * 2048 + wpos);
            oacc[t] = __builtin_amdgcn_mfma_f32_16x16x32_bf16(pa, vf, oacc[t], 0, 0, 0);
        }
    }

    // ---- epilogue: normalize, write single bf16 for out-GEMM ----
    float linv[4];
#pragma unroll
    for (int e = 0; e < 4; ++e) {
        const int r32 = mi * 16 + quad * 4 + e;
        linv[e] = 1.0f / (psum[0][r32] + psum[1][r32] + psum[2][r32] + psum[3][r32]);
    }
#pragma unroll
    for (int t = 0; t < 2; ++t) {
        const int nj = (wv & 1) * 2 + t;
#pragma unroll
        for (int e = 0; e < 4; ++e) {
            const int r32 = mi * 16 + quad * 4 + e;
            const float val = oacc[t][e] * linv[e];
            const size_t idx = (size_t)(t0 + r32) * 512 + h * 64 + nj * 16 + col;
            abh[idx] = bfh(val);
        }
    }
}

// ---------------------------------------------------------------------------
extern "C" void kernel_launch(void* const* d_in, const int* in_sizes, int n_in,
                              void* d_out, int out_size, void* d_ws, size_t ws_size,
                              hipStream_t stream)
{
    const float* x  = (const float*)d_in[0];
    const float* Wq = (const float*)d_in[1];
    const float* bq = (const float*)d_in[2];
    const float* Wk = (const float*)d_in[3];
    const float* bk = (const float*)d_in[4];
    const float* Wv = (const float*)d_in[5];
    const float* bv = (const float*)d_in[6];
    const float* Wo = (const float*)d_in[7];
    const float* bo = (const float*)d_in[8];
    float* out = (float*)d_out;

    char* ws = (char*)d_ws;
    short* qh  = (short*)(ws);                          // 2 MB
    short* ql  = (short*)(ws + (2u << 20));             // 2 MB
    short* kb  = (short*)(ws + (4u << 20));             // 2 MB
    short* vbt = (short*)(ws + (6u << 20));             // 2 MB (transposed V)
    short* abh = (short*)(ws + (8u << 20));             // 2 MB (attn out bf16)
    short* wqb = (short*)(ws + (12u << 20));            // 0.5 MB each
    short* wkb = (short*)(ws + (12u << 20) + 1 * (512u << 10));
    short* wvb = (short*)(ws + (12u << 20) + 2 * (512u << 10));
    short* wob = (short*)(ws + (12u << 20) + 3 * (512u << 10));

    dim3 gw(64, 1, 4);
    cast_w<<<gw, 256, 0, stream>>>(Wq, Wk, Wv, Wo, wqb, wkb, wvb, wob);

    dim3 gq(DMODEL / 64, S_LEN / 64, 3);                // 8 x 32 x 3 = 768 blocks
    gemm_qkv6<<<gq, 256, 0, stream>>>(x, wqb, wkb, wvb,
                                      bq, bk, bv, qh, ql, kb, vbt);

    dim3 ga(NHEADS, S_LEN / 32);                        // 512 blocks
    banded_attn5<<<ga, 256, 0, stream>>>(qh, ql, kb, vbt, abh);

    dim3 go(DMODEL / 64, S_LEN / 32);                   // 8 x 64 = 512 blocks
    gemm_out6<<<go, 128, 0, stream>>>(abh, wob, bo, out);
}

// Round 10
// 112.251 us; speedup vs baseline: 1.2024x; 1.2024x over previous
//
#include <hip/hip_runtime.h>
#include <hip/hip_bf16.h>
#include <math.h>

#define S_LEN  2048
#define DMODEL 512
#define NHEADS 8
#define DK     64
#define WIN    64

static constexpr float SCALE = 0.125f;

typedef short bf16x8 __attribute__((ext_vector_type(8)));
typedef float f32x4  __attribute__((ext_vector_type(4)));

// ---------------------------------------------------------------------------
// helpers
// ---------------------------------------------------------------------------
__device__ __forceinline__ short bfh(float v)
{
    __hip_bfloat16 b = __float2bfloat16(v);
    return *reinterpret_cast<short*>(&b);
}
__device__ __forceinline__ float bf2f(short s)
{
    __hip_bfloat16 b = *reinterpret_cast<__hip_bfloat16*>(&s);
    return __bfloat162float(b);
}
__device__ __forceinline__ void split1(float v, short& h, short& l)
{
    h = bfh(v);
    l = bfh(v - bf2f(h));
}

// async global->LDS, 16B per lane; lds dest = wave-uniform base + lane*16
__device__ __forceinline__ void dma16(const void* g, void* l)
{
    __builtin_amdgcn_global_load_lds(
        (const __attribute__((address_space(1))) unsigned int*)g,
        (__attribute__((address_space(3))) unsigned int*)l, 16, 0, 0);
}

// ---------------------------------------------------------------------------
// prep: z=0 -> x split into (xh, xl); z=1..4 -> W cast to bf16
// ---------------------------------------------------------------------------
__global__ __launch_bounds__(256)
void prep(const float* __restrict__ x,
          const float* __restrict__ wq, const float* __restrict__ wk,
          const float* __restrict__ wv, const float* __restrict__ wo,
          short* __restrict__ xh, short* __restrict__ xl,
          short* __restrict__ wqb, short* __restrict__ wkb,
          short* __restrict__ wvb, short* __restrict__ wob)
{
    const int z = blockIdx.z;
    if (z == 0) {
        for (int i = blockIdx.x * 256 + threadIdx.x; i < 262144; i += gridDim.x * 256) {
            const float4 v = ((const float4*)x)[i];
            short4 h4, l4;
            split1(v.x, h4.x, l4.x);
            split1(v.y, h4.y, l4.y);
            split1(v.z, h4.z, l4.z);
            split1(v.w, h4.w, l4.w);
            ((short4*)xh)[i] = h4;
            ((short4*)xl)[i] = l4;
        }
    } else {
        const float* s; short* d;
        switch (z) {
            case 1:  s = wq; d = wqb; break;
            case 2:  s = wk; d = wkb; break;
            case 3:  s = wv; d = wvb; break;
            default: s = wo; d = wob; break;
        }
        for (int i = blockIdx.x * 256 + threadIdx.x; i < 65536; i += gridDim.x * 256) {
            const float4 v = ((const float4*)s)[i];
            short4 o;
            o.x = bfh(v.x); o.y = bfh(v.y); o.z = bfh(v.z); o.w = bfh(v.w);
            ((short4*)d)[i] = o;
        }
    }
}

// ---------------------------------------------------------------------------
// QKV GEMM: 32-row x 64-col tiles, grid (8,64,3) = 1536 blocks (6/CU),
// 128 thr = 2 waves. W (bf16) staged via DMA in 4 phases x 16 KB with
// XOR chunk swizzle; A = pre-split xh/xl read straight from global.
// Inner loop is pure load + ds_read + MFMA (no conversion VALU).
// z=0 -> Q bf16, z=1 -> K bf16, z=2 -> V^T bf16 [dim][pos].
// ---------------------------------------------------------------------------
__global__ __launch_bounds__(128)
void gemm_qkv7(const short* __restrict__ xh, const short* __restrict__ xl,
               const short* __restrict__ wqb, const short* __restrict__ wkb,
               const short* __restrict__ wvb,
               const float* __restrict__ bq, const float* __restrict__ bk,
               const float* __restrict__ bv,
               short* __restrict__ qb, short* __restrict__ kb,
               short* __restrict__ vbt)
{
    __shared__ __align__(16) short sW[64 * 128];   // 16 KB: 64 cols x 128 k

    const int z = blockIdx.z;
    const short* Bg   = (z == 0) ? wqb : (z == 1) ? wkb : wvb;
    const float* bias = (z == 0) ? bq  : (z == 1) ? bk  : bv;
    const int row0 = blockIdx.y * 32;
    const int col0 = blockIdx.x * 64;
    const int tid  = threadIdx.x;
    const int lane = tid & 63;
    const int wv   = tid >> 6;
    const int col  = lane & 15;
    const int quad = lane >> 4;
    const int m    = row0 + wv * 16 + col;       // this wave's A row

    f32x4 acc[4];
#pragma unroll
    for (int nj = 0; nj < 4; ++nj)
        acc[nj] = (f32x4)0.0f;

    for (int ph = 0; ph < 4; ++ph) {
        __syncthreads();   // previous phase's LDS reads done
        // stage 64 rows x 16 chunks (16B) = 16 issues; issue i = rows 4i..4i+3
        for (int i = wv; i < 16; i += 2) {
            const int r = i * 4 + (lane >> 4);
            const int c = lane & 15;
            const int j = c ^ (r & 7);
            dma16(Bg + (size_t)(col0 + r) * 512 + ph * 128 + j * 8, sW + i * 512);
        }
        __syncthreads();   // DMA drain

#pragma unroll
        for (int kc = 0; kc < 4; ++kc) {
            const size_t aoff = (size_t)m * 512 + ph * 128 + kc * 32 + quad * 8;
            const bf16x8 ah = *(const bf16x8*)(xh + aoff);
            const bf16x8 al = *(const bf16x8*)(xl + aoff);
#pragma unroll
            for (int nj = 0; nj < 4; ++nj) {
                const int n = nj * 16 + col;
                const int c = kc * 4 + quad;
                const bf16x8 bf = *(const bf16x8*)&sW[n * 128 + (c ^ (n & 7)) * 8];
                acc[nj] = __builtin_amdgcn_mfma_f32_16x16x32_bf16(ah, bf, acc[nj], 0, 0, 0);
                acc[nj] = __builtin_amdgcn_mfma_f32_16x16x32_bf16(al, bf, acc[nj], 0, 0, 0);
            }
        }
    }

    // epilogue
#pragma unroll
    for (int nj = 0; nj < 4; ++nj) {
        const int cc = col0 + nj * 16 + col;
        const float bias_v = bias[cc];
#pragma unroll
        for (int e = 0; e < 4; ++e) {
            const int row = row0 + wv * 16 + quad * 4 + e;
            const float val = acc[nj][e] + bias_v;
            if (z == 0) {
                qb[(size_t)row * 512 + cc] = bfh(val);        // single bf16 Q
            } else if (z == 1) {
                kb[(size_t)row * 512 + cc] = bfh(val);
            } else {
                vbt[(size_t)cc * 2048 + row] = bfh(val);      // transposed
            }
        }
    }
}

// ---------------------------------------------------------------------------
// Output projection: same staging shape; A = attn output bf16 (direct).
// grid (8,64) = 512 blocks, 128 thr.
// ---------------------------------------------------------------------------
__global__ __launch_bounds__(128)
void gemm_out7(const short* __restrict__ ah_g,
               const short* __restrict__ wob, const float* __restrict__ bo,
               float* __restrict__ out)
{
    __shared__ __align__(16) short sW[64 * 128];   // 16 KB

    const int row0 = blockIdx.y * 32;
    const int col0 = blockIdx.x * 64;
    const int tid  = threadIdx.x;
    const int lane = tid & 63;
    const int wv   = tid >> 6;
    const int col  = lane & 15;
    const int quad = lane >> 4;
    const int m    = row0 + wv * 16 + col;

    f32x4 acc[4];
#pragma unroll
    for (int nj = 0; nj < 4; ++nj)
        acc[nj] = (f32x4)0.0f;

    for (int ph = 0; ph < 4; ++ph) {
        __syncthreads();
        for (int i = wv; i < 16; i += 2) {
            const int r = i * 4 + (lane >> 4);
            const int c = lane & 15;
            const int j = c ^ (r & 7);
            dma16(wob + (size_t)(col0 + r) * 512 + ph * 128 + j * 8, sW + i * 512);
        }
        __syncthreads();

#pragma unroll
        for (int kc = 0; kc < 4; ++kc) {
            const bf16x8 af = *(const bf16x8*)(ah_g + (size_t)m * 512 + ph * 128 + kc * 32 + quad * 8);
#pragma unroll
            for (int nj = 0; nj < 4; ++nj) {
                const int n = nj * 16 + col;
                const int c = kc * 4 + quad;
                const bf16x8 bf = *(const bf16x8*)&sW[n * 128 + (c ^ (n & 7)) * 8];
                acc[nj] = __builtin_amdgcn_mfma_f32_16x16x32_bf16(af, bf, acc[nj], 0, 0, 0);
            }
        }
    }

#pragma unroll
    for (int nj = 0; nj < 4; ++nj) {
        const int cc = col0 + nj * 16 + col;
        const float bias_v = bo[cc];
#pragma unroll
        for (int e = 0; e < 4; ++e) {
            const int row = row0 + wv * 16 + quad * 4 + e;
            out[(size_t)row * 512 + cc] = acc[nj][e] + bias_v;
        }
    }
}

// ---------------------------------------------------------------------------
// MFMA banded attention (R7 body, Q single bf16). Block = (head, 32-q tile),
// 256 thr = 4 waves. Q/K staged via DMA w/ XOR(row&7) chunk swizzle; V^T
// staged via DMA from pre-transposed vbt. P through LDS (layout transform).
// ---------------------------------------------------------------------------
__global__ __launch_bounds__(256)
void banded_attn6(const short* __restrict__ qb, const short* __restrict__ kb,
                  const short* __restrict__ vbt, short* __restrict__ abh)
{
    __shared__ __align__(16) short VtS[64 * 256];   // V^T [dim][32 chunks]
    __shared__ __align__(16) short KS [192 * 64];   // K window; aliased by P
    __shared__ __align__(16) short QS [32 * 64];
    __shared__ float pmax[4][32];
    __shared__ float psum[4][32];
    short* PS = KS;                                 // P [32][200], after QK

    const int h    = blockIdx.x;
    const int t0   = blockIdx.y * 32;
    const int tid  = threadIdx.x;
    const int lane = tid & 63;
    const int wv   = tid >> 6;
    const int col  = lane & 15;
    const int quad = lane >> 4;

    // ---- DMA staging: Q (4 issues), K (24) — 8-row groups of 128B ----
    {
        const int lr = lane >> 3;
        const int lc = lane & 7;
        for (int i = wv; i < 28; i += 4) {
            const short* src; short* dst; int r;
            if (i < 4) {
                r = i * 8 + lr;
                src = qb + (size_t)(t0 + r) * 512 + h * 64;
                dst = QS + i * 512;
            } else {
                const int g = i - 4;
                r = g * 8 + lr;
                int pos = t0 - 64 + r;
                pos = pos < 0 ? 0 : (pos > 2047 ? 2047 : pos);   // masked later
                src = kb + (size_t)pos * 512 + h * 64;
                dst = KS + g * 512;
            }
            const int cs = lc ^ (r & 7);
            dma16(src + cs * 8, dst);
        }
        // ---- V^T window: 64 dims x 24 chunks (192 pos), rows padded to 32 ----
        for (int i = wv; i < 32; i += 4) {
            const int q = i * 64 + lane;
            const int d = q >> 5;            // dim 0..63
            const int b = q & 31;            // dest chunk in row
            const int j0 = (b < 24) ? b : 0; // dead chunks load dummy
            const int j = j0 ^ (d & 7);
            int p0 = t0 - 64 + j * 8;
            p0 = p0 < 0 ? 0 : (p0 > 2040 ? 2040 : p0);
            dma16(vbt + (size_t)(h * 64 + d) * 2048 + p0, VtS + i * 512);
        }
    }
    __syncthreads();

    // ---- QK^T: wave covers positions [wv*48, wv*48+48) ----
    f32x4 sacc[2][3];
#pragma unroll
    for (int mi = 0; mi < 2; ++mi)
#pragma unroll
        for (int nj = 0; nj < 3; ++nj)
            sacc[mi][nj] = (f32x4)0.0f;

#pragma unroll
    for (int ks = 0; ks < 2; ++ks) {
        const int q0 = ks * 4 + quad;
        bf16x8 aq[2];
#pragma unroll
        for (int mi = 0; mi < 2; ++mi) {
            const int mm = mi * 16 + col;
            const int p = q0 ^ (mm & 7);
            aq[mi] = *(const bf16x8*)&QS[mm * 64 + p * 8];
        }
#pragma unroll
        for (int nj = 0; nj < 3; ++nj) {
            const int n = wv * 48 + nj * 16 + col;
            const int p = q0 ^ (n & 7);
            const bf16x8 bkf = *(const bf16x8*)&KS[n * 64 + p * 8];
#pragma unroll
            for (int mi = 0; mi < 2; ++mi)
                sacc[mi][nj] = __builtin_amdgcn_mfma_f32_16x16x32_bf16(aq[mi], bkf, sacc[mi][nj], 0, 0, 0);
        }
    }

    // ---- mask + scale ----
    float pv[2][3][4];
#pragma unroll
    for (int mi = 0; mi < 2; ++mi)
#pragma unroll
        for (int nj = 0; nj < 3; ++nj)
#pragma unroll
            for (int e = 0; e < 4; ++e) {
                const int r32 = mi * 16 + quad * 4 + e;
                const int n   = wv * 48 + nj * 16 + col;
                const int pos = t0 - 64 + n;
                const int d   = n - r32;
                const bool valid = (pos >= 0) && (pos < S_LEN) && (d >= 0) && (d <= 128);
                pv[mi][nj][e] = valid ? sacc[mi][nj][e] * SCALE : -__builtin_inff();
            }

    // ---- wave-partial row max ----
#pragma unroll
    for (int mi = 0; mi < 2; ++mi)
#pragma unroll
        for (int e = 0; e < 4; ++e) {
            float mx = fmaxf(fmaxf(pv[mi][0][e], pv[mi][1][e]), pv[mi][2][e]);
#pragma unroll
            for (int off = 1; off < 16; off <<= 1)
                mx = fmaxf(mx, __shfl_xor(mx, off));
            if ((lane & 15) == 0) pmax[wv][mi * 16 + quad * 4 + e] = mx;
        }
    __syncthreads();   // pmax done; K/Q reads done -> P may overwrite KS

    // ---- exp + wave-partial sums + write P (bf16) ----
#pragma unroll
    for (int mi = 0; mi < 2; ++mi)
#pragma unroll
        for (int e = 0; e < 4; ++e) {
            const int r32 = mi * 16 + quad * 4 + e;
            const float m = fmaxf(fmaxf(pmax[0][r32], pmax[1][r32]),
                                  fmaxf(pmax[2][r32], pmax[3][r32]));
            float ss = 0.f;
#pragma unroll
            for (int nj = 0; nj < 3; ++nj) {
                const float p = __expf(pv[mi][nj][e] - m);
                pv[mi][nj][e] = p;
                ss += p;
            }
#pragma unroll
            for (int off = 1; off < 16; off <<= 1)
                ss += __shfl_xor(ss, off);
            if ((lane & 15) == 0) psum[wv][r32] = ss;
#pragma unroll
            for (int nj = 0; nj < 3; ++nj) {
                const int n = wv * 48 + nj * 16 + col;
                PS[r32 * 200 + n] = bfh(pv[mi][nj][e]);
            }
        }
    __syncthreads();

    // ---- PV ----
    const int mi = wv >> 1;
    f32x4 oacc[2];
    oacc[0] = (f32x4)0.0f;
    oacc[1] = (f32x4)0.0f;
#pragma unroll
    for (int ks = 0; ks < 6; ++ks) {
        const bf16x8 pa = *(const bf16x8*)&PS[(mi * 16 + col) * 200 + ks * 32 + quad * 8];
#pragma unroll
        for (int t = 0; t < 2; ++t) {
            const int d = ((wv & 1) * 2 + t) * 16 + col;
            const int j = (ks * 4 + quad) ^ (d & 7);
            const bf16x8 vf = *(const bf16x8*)&VtS[d * 256 + j * 8];
            oacc[t] = __builtin_amdgcn_mfma_f32_16x16x32_bf16(pa, vf, oacc[t], 0, 0, 0);
        }
    }

    // ---- epilogue: normalize, write bf16 for out-GEMM ----
    float linv[4];
#pragma unroll
    for (int e = 0; e < 4; ++e) {
        const int r32 = mi * 16 + quad * 4 + e;
        linv[e] = 1.0f / (psum[0][r32] + psum[1][r32] + psum[2][r32] + psum[3][r32]);
    }
#pragma unroll
    for (int t = 0; t < 2; ++t) {
        const int nj = (wv & 1) * 2 + t;
#pragma unroll
        for (int e = 0; e < 4; ++e) {
            const int r32 = mi * 16 + quad * 4 + e;
            const float val = oacc[t][e] * linv[e];
            const size_t idx = (size_t)(t0 + r32) * 512 + h * 64 + nj * 16 + col;
            abh[idx] = bfh(val);
        }
    }
}

// ---------------------------------------------------------------------------
extern "C" void kernel_launch(void* const* d_in, const int* in_sizes, int n_in,
                              void* d_out, int out_size, void* d_ws, size_t ws_size,
                              hipStream_t stream)
{
    const float* x  = (const float*)d_in[0];
    const float* Wq = (const float*)d_in[1];
    const float* bq = (const float*)d_in[2];
    const float* Wk = (const float*)d_in[3];
    const float* bk = (const float*)d_in[4];
    const float* Wv = (const float*)d_in[5];
    const float* bv = (const float*)d_in[6];
    const float* Wo = (const float*)d_in[7];
    const float* bo = (const float*)d_in[8];
    float* out = (float*)d_out;

    char* ws = (char*)d_ws;
    short* qb  = (short*)(ws);                          // 2 MB
    short* kb  = (short*)(ws + (2u << 20));             // 2 MB
    short* vbt = (short*)(ws + (4u << 20));             // 2 MB (transposed V)
    short* abh = (short*)(ws + (6u << 20));             // 2 MB (attn out bf16)
    short* xh  = (short*)(ws + (8u << 20));             // 2 MB
    short* xl  = (short*)(ws + (10u << 20));            // 2 MB
    short* wqb = (short*)(ws + (12u << 20));            // 0.5 MB each
    short* wkb = (short*)(ws + (12u << 20) + 1 * (512u << 10));
    short* wvb = (short*)(ws + (12u << 20) + 2 * (512u << 10));
    short* wob = (short*)(ws + (12u << 20) + 3 * (512u << 10));

    dim3 gp(128, 1, 5);
    prep<<<gp, 256, 0, stream>>>(x, Wq, Wk, Wv, Wo,
                                 xh, xl, wqb, wkb, wvb, wob);

    dim3 gq(DMODEL / 64, S_LEN / 32, 3);                // 8 x 64 x 3 = 1536 blocks
    gemm_qkv7<<<gq, 128, 0, stream>>>(xh, xl, wqb, wkb, wvb,
                                      bq, bk, bv, qb, kb, vbt);

    dim3 ga(NHEADS, S_LEN / 32);                        // 512 blocks
    banded_attn6<<<ga, 256, 0, stream>>>(qb, kb, vbt, abh);

    dim3 go(DMODEL / 64, S_LEN / 32);                   // 8 x 64 = 512 blocks
    gemm_out7<<<go, 128, 0, stream>>>(abh, wob, bo, out);
}